// Round 8
// baseline (469.222 us; speedup 1.0000x reference)
//
#include <hip/hip_runtime.h>
#include <math.h>

// ---- problem constants ----
#define TB        256           // threads per block = 4 waves
#define POSB      64            // positions per block
#define NPOS      131072        // B*H*W positions
#define KCODES    512
#define DIM       64
#define HW        4096          // H*W
#define LOSS_OFF  8388608ull
#define ENC_OFF   8388609ull
#define PERP_OFF  75497473ull
#define TILE_DW   (POSB * KCODES)       // 32768 dwords: block's encodings tile
#define NF4       ((TILE_DW - 4) / 4)   // 8191 float4 after the +3 align shift
#define TAU       2.0e-4f               // rigorous screen slack (R12 notes)

typedef __attribute__((ext_vector_type(8))) short bf16x8;   // 8 bf16 = 4 VGPR
typedef __attribute__((ext_vector_type(4))) float f32x4;

__device__ __forceinline__ float tree8(float r0, float r1, float r2, float r3,
                                       float r4, float r5, float r6, float r7) {
    // numpy pairwise combine: ((r0+r1)+(r2+r3)) + ((r4+r5)+(r6+r7))
    return __fadd_rn(__fadd_rn(__fadd_rn(r0, r1), __fadd_rn(r2, r3)),
                     __fadd_rn(__fadd_rn(r4, r5), __fadd_rn(r6, r7)));
}

// Prep (unchanged): ww[k] exact pairwise; w packed into MFMA B-fragments
// (bf16 hi/lo truncation split: hi = top-16 bits, lo = trunc(v-hi)).
// B-frag convention (16x16x32): lane lf holds col n = lf&15, k = (lf>>4)*8+j.
extern "C" __global__ __launch_bounds__(512)
void vq_prep(const float* __restrict__ w, float* __restrict__ ww,
             int* __restrict__ counts, float* __restrict__ lossAcc,
             unsigned short* __restrict__ wfrag)
{
    const int k = threadIdx.x;                 // 512 threads = codes
    const float* wk = w + k * DIM;
    const int ct = k >> 4, n = k & 15;
    float r[8];
    #pragma unroll
    for (int i = 0; i < 8; ++i) {
        #pragma unroll
        for (int j = 0; j < 8; ++j) {
            const int d = i * 8 + j;
            float v = wk[d];
            float pp = __fmul_rn(v, v);
            r[j] = (i == 0) ? pp : __fadd_rn(r[j], pp);
            unsigned int hb = __float_as_uint(v) & 0xFFFF0000u;
            float rr = v - __uint_as_float(hb);            // exact residual
            unsigned short hs = (unsigned short)(hb >> 16);
            unsigned short ls = (unsigned short)(__float_as_uint(rr) >> 16);
            const int q = d >> 5, kk = d & 31;
            const int lf = ((kk >> 3) << 4) + n, j8 = kk & 7;
            wfrag[((((0 * 32 + ct) * 2 + q) * 64 + lf) << 3) + j8] = hs;
            wfrag[((((1 * 32 + ct) * 2 + q) * 64 + lf) << 3) + j8] = ls;
        }
    }
    ww[k] = tree8(r[0], r[1], r[2], r[3], r[4], r[5], r[6], r[7]);
    counts[k] = 0;
    if (k == 0) *lossAcc = 0.0f;
}

// R14: R13's MFMA screen + exact rescue, with ALL encodings traffic removed.
// R6-R13 post-mortem: three different compute structures (s_load chain, LDS
// score staging, register screen) all pinned at ~185us. The invariant was the
// 268MB zero-fill interleaved into load-dependent loops: stores and loads
// share vmcnt, so every compiler wait before a w/FRAG load use also waits on
// outstanding zero-fill stores (~600cy acks under HBM write pressure) ->
// store-drain gated every iteration. Here vq_main emits only bestk (256KB
// ushort, coalesced) + quantized (33.5MB, epilogue-only) + loss/counts; the
// encodings region is written by the dedicated streaming kernel vq_enc.
// Screen/rescue decisions and all written values bit-identical to R12/R13.
#define FRAG(PART, CT, Q) wf[((((PART) * 32 + (CT)) * 2 + (Q)) * 64) + l]

#define TILE6(BH0, BH1, BL0, BL1, WWK)                                        \
    acc = (f32x4){(WWK), (WWK), (WWK), (WWK)};                                \
    acc = __builtin_amdgcn_mfma_f32_16x16x32_bf16(aL0, BH0, acc, 0, 0, 0);    \
    acc = __builtin_amdgcn_mfma_f32_16x16x32_bf16(aH0, BL0, acc, 0, 0, 0);    \
    acc = __builtin_amdgcn_mfma_f32_16x16x32_bf16(aH0, BH0, acc, 0, 0, 0);    \
    acc = __builtin_amdgcn_mfma_f32_16x16x32_bf16(aL1, BH1, acc, 0, 0, 0);    \
    acc = __builtin_amdgcn_mfma_f32_16x16x32_bf16(aH1, BL1, acc, 0, 0, 0);    \
    acc = __builtin_amdgcn_mfma_f32_16x16x32_bf16(aH1, BH1, acc, 0, 0, 0);

extern "C" __global__ __launch_bounds__(TB)
__attribute__((amdgpu_waves_per_eu(3, 8)))
void vq_main(const float* __restrict__ x, const float* __restrict__ w,
             const float* __restrict__ ww, float* __restrict__ out,
             int* __restrict__ counts, float* __restrict__ lossAcc,
             const unsigned short* __restrict__ wfrag,
             unsigned short* __restrict__ bkg)
{
    __shared__ __align__(16) float xtile[DIM][65];   // 16640 B, pad -> <=2-way
    __shared__ float wwlds[KCODES];                  //  2048 B
    __shared__ int   hcount[KCODES];                 //  2048 B
    __shared__ int   ccount[POSB];                   //   256 B
    __shared__ int   clist[POSB * 4];                //  1024 B
    __shared__ int   bestkL[POSB];                   //   256 B

    const int tid = threadIdx.x;
    const int l   = tid & 63;                  // lane
    const int wv  = tid >> 6;                  // wave id
    const int n0  = blockIdx.x * POSB;         // 64 | 4096: one b per block
    const int b   = n0 >> 12;
    const int hw0 = n0 & 4095;

    hcount[tid]      = 0;
    hcount[tid + TB] = 0;
    if (tid < POSB) ccount[tid] = 0;
    wwlds[tid]      = ww[tid];                 // staged once, coalesced
    wwlds[tid + TB] = ww[tid + TB];

    // ---- A: cooperative x-tile load (fully coalesced: 256B/wave-instr)
    const float* xb = x + ((size_t)b * DIM) * HW + hw0;
    #pragma unroll
    for (int it = 0; it < 16; ++it) {
        const int idx = it * TB + tid;
        const int d = idx >> 6, ps = idx & 63;
        xtile[d][ps] = xb[(size_t)d * HW + ps];
    }
    __syncthreads();   // xtile + wwlds + ccount ready

    // ---- B: each wave builds A-fragments of -2x for ITS pos-tile (rows =
    // positions wv*16+(l&15); k = (l>>4)*8+j8, channel d = q*32+k — matches
    // the R12-verified A/B k-convention, so any permutation cancels).
    bf16x8 aH0, aH1, aL0, aL1;
    {
        const int arow = wv * 16 + (l & 15);
        #pragma unroll
        for (int q = 0; q < 2; ++q) {
            #pragma unroll
            for (int j8 = 0; j8 < 8; ++j8) {
                const int d = q * 32 + ((l >> 4) << 3) + j8;
                float v = xtile[d][arow];
                float m2 = -(v + v);                 // exact
                unsigned int hb = __float_as_uint(m2) & 0xFFFF0000u;
                float rr = m2 - __uint_as_float(hb);
                short hs = (short)(hb >> 16);
                short ls = (short)(__float_as_uint(rr) >> 16);
                if (q == 0) { aH0[j8] = hs; aL0[j8] = ls; }
                else        { aH1[j8] = hs; aL1[j8] = ls; }
            }
        }
    }

    const bf16x8* wf = reinterpret_cast<const bf16x8*>(wfrag);
    const int rb = wv * 16 + ((l >> 4) << 2);  // acc[i] -> local row rb+i

    // ---- C: sweep 1 — running per-row min in registers (clean vmcnt chain:
    // the ONLY VMEM in this loop is the FRAG prefetch loads)
    float rmin[4] = { INFINITY, INFINITY, INFINITY, INFINITY };
    {
        bf16x8 c0 = FRAG(0, 0, 0), c1 = FRAG(0, 0, 1);
        bf16x8 c2 = FRAG(1, 0, 0), c3 = FRAG(1, 0, 1);
        float wa = wwlds[(l & 15)];
        f32x4 acc;
        #pragma unroll 1
        for (int ct = 0; ct < 32; ct += 2) {
            bf16x8 n0_ = FRAG(0, ct + 1, 0), n1_ = FRAG(0, ct + 1, 1);
            bf16x8 n2_ = FRAG(1, ct + 1, 0), n3_ = FRAG(1, ct + 1, 1);
            float wb = wwlds[(ct + 1) * 16 + (l & 15)];
            TILE6(c0, c1, c2, c3, wa)
            #pragma unroll
            for (int i = 0; i < 4; ++i) rmin[i] = fminf(rmin[i], acc[i]);
            const int t2 = (ct + 2) & 31;                // tail wraps; harmless
            c0 = FRAG(0, t2, 0); c1 = FRAG(0, t2, 1);
            c2 = FRAG(1, t2, 0); c3 = FRAG(1, t2, 1);
            wa = wwlds[t2 * 16 + (l & 15)];
            TILE6(n0_, n1_, n2_, n3_, wb)
            #pragma unroll
            for (int i = 0; i < 4; ++i) rmin[i] = fminf(rmin[i], acc[i]);
        }
    }
    // col-reduce: 16-lane butterfly (lanes sharing l>>4 hold cols 0..15)
    #pragma unroll
    for (int mm = 1; mm < 16; mm <<= 1) {
        #pragma unroll
        for (int i = 0; i < 4; ++i)
            rmin[i] = fminf(rmin[i], __shfl_xor(rmin[i], mm));
    }
    float thr[4];
    #pragma unroll
    for (int i = 0; i < 4; ++i) thr[i] = rmin[i] + TAU;

    // ---- D: sweep 2 — bit-identical recompute, candidate append vs thr
    {
        bf16x8 c0 = FRAG(0, 0, 0), c1 = FRAG(0, 0, 1);
        bf16x8 c2 = FRAG(1, 0, 0), c3 = FRAG(1, 0, 1);
        float wa = wwlds[(l & 15)];
        f32x4 acc;
        #pragma unroll 1
        for (int ct = 0; ct < 32; ct += 2) {
            bf16x8 n0_ = FRAG(0, ct + 1, 0), n1_ = FRAG(0, ct + 1, 1);
            bf16x8 n2_ = FRAG(1, ct + 1, 0), n3_ = FRAG(1, ct + 1, 1);
            float wb = wwlds[(ct + 1) * 16 + (l & 15)];
            TILE6(c0, c1, c2, c3, wa)
            #pragma unroll
            for (int i = 0; i < 4; ++i) {
                if (acc[i] <= thr[i]) {
                    int s = atomicAdd(&ccount[rb + i], 1);
                    if (s < 4) clist[(rb + i) * 4 + s] = ct * 16 + (l & 15);
                }
            }
            const int t2 = (ct + 2) & 31;
            c0 = FRAG(0, t2, 0); c1 = FRAG(0, t2, 1);
            c2 = FRAG(1, t2, 0); c3 = FRAG(1, t2, 1);
            wa = wwlds[t2 * 16 + (l & 15)];
            TILE6(n0_, n1_, n2_, n3_, wb)
            #pragma unroll
            for (int i = 0; i < 4; ++i) {
                if (acc[i] <= thr[i]) {
                    int s = atomicAdd(&ccount[rb + i], 1);
                    if (s < 4) clist[(rb + i) * 4 + s] = (ct + 1) * 16 + (l & 15);
                }
            }
        }
    }

    __syncthreads();   // clists complete

    // ---- E: rescue (wave 0, lane l = position n0+l); exact chain only for
    // multi-candidate lanes (~3%), token-identical to the reference order.
    if (wv == 0) {
        const int cnt = ccount[l];
        int bk;
        if (cnt == 1) {
            bk = clist[l * 4 + 0];
        } else {
            float x2c[DIM];
            float r[8];
            #pragma unroll
            for (int d = 0; d < DIM; ++d) {
                float v = xtile[d][l];
                x2c[d] = v + v;                  // exact doubling
                float pp = __fmul_rn(v, v);
                r[d & 7] = (d < 8) ? pp : __fadd_rn(r[d & 7], pp);
            }
            const float A = tree8(r[0], r[1], r[2], r[3], r[4], r[5], r[6], r[7]);
            if (cnt <= 4) {
                float bd = INFINITY; int bk2 = KCODES;
                for (int c = 0; c < cnt; ++c) {
                    const int k = clist[l * 4 + c];
                    const float* wk = w + (size_t)k * DIM;
                    float s[8];
                    #pragma unroll
                    for (int i = 0; i < 8; ++i) {
                        #pragma unroll
                        for (int j = 0; j < 8; ++j) {
                            const int d = i * 8 + j;
                            float wvv = wk[d];
                            if (i == 0) s[j] = __fmul_rn(x2c[d], wvv);
                            else        s[j] = __fmaf_rn(x2c[d], wvv, s[j]);
                        }
                    }
                    float dot  = tree8(s[0], s[1], s[2], s[3], s[4], s[5], s[6], s[7]);
                    float dist = __fadd_rn(__fadd_rn(A, wwlds[k]), -dot);
                    if (dist < bd || (dist == bd && k < bk2)) { bd = dist; bk2 = k; }
                }
                bk = bk2;
            } else {                             // guaranteed path (≈never)
                float bd = INFINITY; int bk2 = 0;
                #pragma unroll 1
                for (int k = 0; k < KCODES; ++k) {
                    const float* wk = w + (size_t)k * DIM;
                    float s[8];
                    #pragma unroll
                    for (int i = 0; i < 8; ++i) {
                        #pragma unroll
                        for (int j = 0; j < 8; ++j) {
                            const int d = i * 8 + j;
                            float wvv = wk[d];
                            if (i == 0) s[j] = __fmul_rn(x2c[d], wvv);
                            else        s[j] = __fmaf_rn(x2c[d], wvv, s[j]);
                        }
                    }
                    float dot  = tree8(s[0], s[1], s[2], s[3], s[4], s[5], s[6], s[7]);
                    float dist = __fadd_rn(__fadd_rn(A, wwlds[k]), -dot);
                    if (dist < bd) { bd = dist; bk2 = k; }   // ascending strict <
                }
                bk = bk2;
            }
        }
        bestkL[l] = bk;
        bkg[n0 + l] = (unsigned short)bk;        // coalesced 128B per block
        atomicAdd(&hcount[bk], 1);
    }

    __syncthreads();   // bestkL visible; hcount atomics ordered before drain

    // ---- F: parallel epilogue — thread (q,sp): channels q*16..+15 of pos sp
    {
        const int sp = tid & 63, q = tid >> 6;
        const int bk = bestkL[sp];
        const float4* wr = reinterpret_cast<const float4*>(w + (size_t)bk * DIM);
        float* qo = out + ((size_t)b * DIM) * HW + (hw0 + sp);
        float sse = 0.0f;
        #pragma unroll
        for (int c = 0; c < 4; ++c) {
            float4 qv = wr[q * 4 + c];
            const int ch = q * 16 + c * 4;
            qo[(size_t)(ch + 0) * HW] = qv.x;
            qo[(size_t)(ch + 1) * HW] = qv.y;
            qo[(size_t)(ch + 2) * HW] = qv.z;
            qo[(size_t)(ch + 3) * HW] = qv.w;
            float e0 = qv.x - xtile[ch + 0][sp]; sse = __fmaf_rn(e0, e0, sse);
            float e1 = qv.y - xtile[ch + 1][sp]; sse = __fmaf_rn(e1, e1, sse);
            float e2 = qv.z - xtile[ch + 2][sp]; sse = __fmaf_rn(e2, e2, sse);
            float e3 = qv.w - xtile[ch + 3][sp]; sse = __fmaf_rn(e3, e3, sse);
        }
        #pragma unroll
        for (int off = 32; off > 0; off >>= 1) sse += __shfl_down(sse, off);
        if (l == 0) atomicAdd(lossAcc, sse);
    }

    __syncthreads();   // all hcount traffic done

    // histogram drain
    {
        int c0 = hcount[tid];       if (c0) atomicAdd(&counts[tid], c0);
        int c1 = hcount[tid + TB];  if (c1) atomicAdd(&counts[tid + TB], c1);
    }
}

// R14: dedicated streaming encodings writer. One pass, pure coalesced float4
// stores with the 1.0f inserted in-register (4 compares per float4) — no
// zeros-then-scatter RMW, no loads in the store loop, runs at fill rate.
extern "C" __global__ __launch_bounds__(TB)
void vq_enc(const unsigned short* __restrict__ bkg, float* __restrict__ out)
{
    __shared__ int bkL[POSB];
    const int tid = threadIdx.x;
    const int n0  = blockIdx.x * POSB;
    if (tid < POSB) bkL[tid] = bkg[n0 + tid];
    const size_t T0 = ENC_OFF + (size_t)blockIdx.x * TILE_DW;
    __syncthreads();

    // edge dwords (tile base is odd-dword: +3 shift for 16B alignment)
    if (tid < 3)  out[T0 + tid] = (bkL[0] == tid) ? 1.0f : 0.0f;
    if (tid == 3) out[T0 + (TILE_DW - 1)] = (bkL[POSB - 1] == 511) ? 1.0f : 0.0f;

    float4* zs4 = reinterpret_cast<float4*>(out + T0 + 3);
    #pragma unroll 4
    for (int it = 0; it < 32; ++it) {
        const int m = it * TB + tid;           // 8192 slots cover 8191
        if (m < NF4) {
            const int o0 = 3 + 4 * m;          // in-tile dword of component 0
            float4 v;
            {   // component offsets may straddle a 512-dword position boundary
                const int oa = o0,     pa = oa >> 9, ca = oa & 511;
                const int ob = o0 + 1, pb = ob >> 9, cb = ob & 511;
                const int oc = o0 + 2, pc = oc >> 9, cc = oc & 511;
                const int od = o0 + 3, pd = od >> 9, cd = od & 511;
                v.x = (bkL[pa] == ca) ? 1.0f : 0.0f;
                v.y = (bkL[pb] == cb) ? 1.0f : 0.0f;
                v.z = (bkL[pc] == cc) ? 1.0f : 0.0f;
                v.w = (bkL[pd] == cd) ? 1.0f : 0.0f;
            }
            zs4[m] = v;
        }
    }
}

// Finalize: loss scalar + perplexity from histogram.
extern "C" __global__ __launch_bounds__(512)
void vq_finalize(const int* __restrict__ counts, const float* __restrict__ lossAcc,
                 float* __restrict__ out)
{
    __shared__ double sred[KCODES];
    const int t = threadIdx.x;                 // 512 threads
    double p = (double)counts[t] * (1.0 / (double)NPOS);
    sred[t] = -p * log(p + 1e-10);
    __syncthreads();
    for (int s = KCODES / 2; s > 0; s >>= 1) {
        if (t < s) sred[t] += sred[t + s];
        __syncthreads();
    }
    if (t == 0) {
        out[PERP_OFF] = (float)exp(sred[0]);
        out[LOSS_OFF] = 1.25f * (lossAcc[0] / 8388608.0f);
    }
}

extern "C" void kernel_launch(void* const* d_in, const int* in_sizes, int n_in,
                              void* d_out, int out_size, void* d_ws, size_t ws_size,
                              hipStream_t stream)
{
    const float* x = (const float*)d_in[0];    // [32,64,64,64] fp32
    const float* w = (const float*)d_in[1];    // [512,64] fp32
    float* out = (float*)d_out;

    float* ww              = (float*)d_ws;                       // 512 floats
    int*   counts          = (int*)((char*)d_ws + 2048);         // 512 ints
    float* lossAcc         = (float*)((char*)d_ws + 4096);       // 1 float
    unsigned short* wfrag  = (unsigned short*)((char*)d_ws + 8192);    // 128KB
    unsigned short* bkg    = (unsigned short*)((char*)d_ws + 139264);  // 256KB

    vq_prep<<<1, 512, 0, stream>>>(w, ww, counts, lossAcc, wfrag);
    vq_main<<<NPOS / POSB, TB, 0, stream>>>(x, w, ww, out, counts,
                                            lossAcc, wfrag, bkg);
    vq_enc<<<NPOS / POSB, TB, 0, stream>>>(bkg, out);
    vq_finalize<<<1, 512, 0, stream>>>(counts, lossAcc, out);
}

// Round 9
// 392.351 us; speedup vs baseline: 1.1959x; 1.1959x over previous
//
#include <hip/hip_runtime.h>
#include <math.h>

// ---- problem constants ----
#define TB        256           // threads per block = 4 waves
#define POSB      256           // positions per block (4 waves x 4 pos-tiles x 16)
#define NPOS      131072        // B*H*W positions
#define KCODES    512
#define DIM       64
#define HW        4096          // H*W
#define LOSS_OFF  8388608ull
#define ENC_OFF   8388609ull
#define PERP_OFF  75497473ull
#define TILE_DW   (POSB * KCODES)       // 131072 dwords: block's encodings tile
#define NF4       ((TILE_DW - 4) / 4)   // 32767 float4 after the +3 align shift
#define TAU       2.0e-4f               // rigorous screen slack (R12 notes)

typedef __attribute__((ext_vector_type(8))) short bf16x8;   // 8 bf16 = 4 VGPR
typedef __attribute__((ext_vector_type(4))) float f32x4;

__device__ __forceinline__ float tree8(float r0, float r1, float r2, float r3,
                                       float r4, float r5, float r6, float r7) {
    // numpy pairwise combine: ((r0+r1)+(r2+r3)) + ((r4+r5)+(r6+r7))
    return __fadd_rn(__fadd_rn(__fadd_rn(r0, r1), __fadd_rn(r2, r3)),
                     __fadd_rn(__fadd_rn(r4, r5), __fadd_rn(r6, r7)));
}

// R15 prep: PARALLELIZED (was 1 block doing 65k scattered 2B stores on one CU,
// a serial ~tens-of-us dependency ahead of vq_main). Blocks 0..31: pack code-
// tile ct's B-fragments with coalesced 16B stores (256 active threads, one
// bf16x8 each). Block 32: exact pairwise ww + counts/lossAcc init.
// Fragment convention identical to R12-R14: lane lf holds col n=lf&15,
// kslot=(lf>>4)*8+j8, channel d=q*32+kslot; hi=top-16-bits, lo=trunc(v-hi).
extern "C" __global__ __launch_bounds__(512)
void vq_prep(const float* __restrict__ w, float* __restrict__ ww,
             int* __restrict__ counts, float* __restrict__ lossAcc,
             unsigned short* __restrict__ wfrag)
{
    const int t = threadIdx.x;
    if (blockIdx.x < 32) {
        const int ct = blockIdx.x;
        if (t < 256) {
            const int part = t >> 7, q = (t >> 6) & 1, lf = t & 63;
            const int n = lf & 15, k = ct * 16 + n;
            const float* wk = w + (size_t)k * DIM;
            unsigned short v8[8];
            #pragma unroll
            for (int j8 = 0; j8 < 8; ++j8) {
                const int d = q * 32 + ((lf >> 4) << 3) + j8;
                float v = wk[d];
                unsigned int hb = __float_as_uint(v) & 0xFFFF0000u;
                if (part == 0) {
                    v8[j8] = (unsigned short)(hb >> 16);
                } else {
                    float rr = v - __uint_as_float(hb);    // exact residual
                    v8[j8] = (unsigned short)(__float_as_uint(rr) >> 16);
                }
            }
            bf16x8* dst = reinterpret_cast<bf16x8*>(wfrag);
            dst[((part * 32 + ct) * 2 + q) * 64 + lf] =
                *reinterpret_cast<const bf16x8*>(v8);
        }
    } else {
        // block 32: ww[k] in the exact numpy pairwise order + zero-init
        const int k = t;                       // 512 threads = codes
        const float* wk = w + (size_t)k * DIM;
        float r[8];
        #pragma unroll
        for (int i = 0; i < 8; ++i) {
            #pragma unroll
            for (int j = 0; j < 8; ++j) {
                float v = wk[i * 8 + j];
                float pp = __fmul_rn(v, v);
                r[j] = (i == 0) ? pp : __fadd_rn(r[j], pp);
            }
        }
        ww[k] = tree8(r[0], r[1], r[2], r[3], r[4], r[5], r[6], r[7]);
        counts[k] = 0;
        if (k == 0) *lossAcc = 0.0f;
    }
}

// R15: MFMA screen + exact rescue at 4x arithmetic intensity.
// R14 post-mortem: store-split made it WORSE (enc zero-fill interleaved is
// free); vq_main ~180us across three compute structures. Remaining suspects:
// serial 1-block prep (fixed above), and per-FRAG-load intensity: R13 fed 6
// dependent MFMAs per 8 L2 loads with 1-iter prefetch (can't cover ~200cy).
// Here each wave runs FOUR pos-tiles against every FRAG load: 24 MFMAs / 8
// loads, 4 independent acc chains (matrix-pipe ILP), 4x fewer blocks (512),
// 4x less per-CU wfrag L2 traffic. Screen/rescue math, fragment conventions,
// TAU bound, tie rules: token-identical to R12-R14 (passing at 7.6e-6).
#define FRAG(PART, CT, Q) wf[((((PART) * 32 + (CT)) * 2 + (Q)) * 64) + l]

// 6 MFMAs of the hi/lo split screen for pos-tile PT against B-frags B0..B3
#define TILE6(PT, B0, B1, B2, B3, WWK)                                        \
    acc = (f32x4){(WWK), (WWK), (WWK), (WWK)};                                \
    acc = __builtin_amdgcn_mfma_f32_16x16x32_bf16(aL0[PT], B0, acc, 0, 0, 0); \
    acc = __builtin_amdgcn_mfma_f32_16x16x32_bf16(aH0[PT], B2, acc, 0, 0, 0); \
    acc = __builtin_amdgcn_mfma_f32_16x16x32_bf16(aH0[PT], B0, acc, 0, 0, 0); \
    acc = __builtin_amdgcn_mfma_f32_16x16x32_bf16(aL1[PT], B1, acc, 0, 0, 0); \
    acc = __builtin_amdgcn_mfma_f32_16x16x32_bf16(aH1[PT], B3, acc, 0, 0, 0); \
    acc = __builtin_amdgcn_mfma_f32_16x16x32_bf16(aH1[PT], B1, acc, 0, 0, 0);

extern "C" __global__ __launch_bounds__(TB)
__attribute__((amdgpu_waves_per_eu(2, 8)))
void vq_main(const float* __restrict__ x, const float* __restrict__ w,
             const float* __restrict__ ww, float* __restrict__ out,
             int* __restrict__ counts, float* __restrict__ lossAcc,
             const unsigned short* __restrict__ wfrag)
{
    __shared__ __align__(16) float xtile[DIM][POSB + 1];  // 65792 B, <=2-way
    __shared__ float wwlds[KCODES];                       //  2048 B
    __shared__ int   hcount[KCODES];                      //  2048 B
    __shared__ int   ccount[POSB];                        //  1024 B
    __shared__ int   clist[POSB * 4];                     //  4096 B
    __shared__ int   bestkL[POSB];                        //  1024 B

    const int tid = threadIdx.x;
    const int l   = tid & 63;                  // lane
    const int wv  = tid >> 6;                  // wave id
    const int n0  = blockIdx.x * POSB;         // 256 | 4096: one b per block
    const int b   = n0 >> 12;
    const int hw0 = n0 & 4095;

    hcount[tid]      = 0;
    hcount[tid + TB] = 0;
    ccount[tid]      = 0;
    wwlds[tid]       = ww[tid];                // staged once, coalesced
    wwlds[tid + TB]  = ww[tid + TB];

    // ---- A: cooperative x-tile load (fully coalesced: 256B/wave-instr)
    const float* xb = x + ((size_t)b * DIM) * HW + hw0;
    #pragma unroll
    for (int it = 0; it < 64; ++it) {
        const int idx = it * TB + tid;
        const int d = idx >> 8, ps = idx & 255;
        xtile[d][ps] = xb[(size_t)d * HW + ps];
    }
    __syncthreads();   // xtile + wwlds + ccount ready

    // ---- B: A-fragments of -2x for this wave's FOUR pos-tiles
    // (tile ti = wv*4+pt covers positions ti*16 .. ti*16+15; row = l&15;
    //  kslot = (l>>4)*8+j8, d = q*32+kslot — same convention as wfrag).
    bf16x8 aH0[4], aH1[4], aL0[4], aL1[4];
    #pragma unroll
    for (int pt = 0; pt < 4; ++pt) {
        const int arow = (wv * 4 + pt) * 16 + (l & 15);
        #pragma unroll
        for (int q = 0; q < 2; ++q) {
            #pragma unroll
            for (int j8 = 0; j8 < 8; ++j8) {
                const int d = q * 32 + ((l >> 4) << 3) + j8;
                float v = xtile[d][arow];
                float m2 = -(v + v);                 // exact
                unsigned int hb = __float_as_uint(m2) & 0xFFFF0000u;
                float rr = m2 - __uint_as_float(hb);
                short hs = (short)(hb >> 16);
                short ls = (short)(__float_as_uint(rr) >> 16);
                if (q == 0) { aH0[pt][j8] = hs; aL0[pt][j8] = ls; }
                else        { aH1[pt][j8] = hs; aL1[pt][j8] = ls; }
            }
        }
    }

    const bf16x8* wf = reinterpret_cast<const bf16x8*>(wfrag);
    const int rloc = (l >> 4) << 2;            // acc[i] -> tile-local row rloc+i

    // encodings tile zero-fill setup (T0%4==1 -> +3 shift is 16B-aligned)
    const size_t T0 = ENC_OFF + (size_t)blockIdx.x * TILE_DW;
    float4* zs4 = reinterpret_cast<float4*>(out + T0 + 3);
    const float4 zero4 = make_float4(0.0f, 0.0f, 0.0f, 0.0f);
    if (tid < 3)  out[T0 + tid] = 0.0f;              // edge dwords 0,1,2
    if (tid == 3) out[T0 + (TILE_DW - 1)] = 0.0f;    // edge dword 131071

    // ---- C: sweep 1 — running per-row min in registers, 4 tiles per FRAG set
    float rmin[4][4];
    #pragma unroll
    for (int pt = 0; pt < 4; ++pt)
        #pragma unroll
        for (int i = 0; i < 4; ++i) rmin[pt][i] = INFINITY;
    {
        bf16x8 c0 = FRAG(0, 0, 0), c1 = FRAG(0, 0, 1);
        bf16x8 c2 = FRAG(1, 0, 0), c3 = FRAG(1, 0, 1);
        float wa = wwlds[(l & 15)];
        f32x4 acc;
        #pragma unroll 1
        for (int ct = 0; ct < 32; ++ct) {
            const int nt = (ct + 1) & 31;                // tail wraps; harmless
            bf16x8 p0 = FRAG(0, nt, 0), p1 = FRAG(0, nt, 1);
            bf16x8 p2 = FRAG(1, nt, 0), p3 = FRAG(1, nt, 1);
            float wb = wwlds[nt * 16 + (l & 15)];
            #pragma unroll
            for (int pt = 0; pt < 4; ++pt) {
                TILE6(pt, c0, c1, c2, c3, wa)
                #pragma unroll
                for (int i = 0; i < 4; ++i)
                    rmin[pt][i] = fminf(rmin[pt][i], acc[i]);
            }
            {   // zero-fill interleave: 4 float4/thread/iter -> [0, 16384)
                const int mb = ct * (TB * 2) + tid;
                zs4[mb]              = zero4;
                zs4[mb + TB]         = zero4;
                const int mb2 = (TB * 64) + ct * (TB * 2) + tid;
                zs4[mb2]             = zero4;
                zs4[mb2 + TB]        = zero4;
            }
            c0 = p0; c1 = p1; c2 = p2; c3 = p3; wa = wb;
        }
    }
    // col-reduce: 16-lane butterfly (lanes sharing l>>4 hold cols 0..15)
    float thr[4][4];
    #pragma unroll
    for (int pt = 0; pt < 4; ++pt) {
        #pragma unroll
        for (int mm = 1; mm < 16; mm <<= 1)
            #pragma unroll
            for (int i = 0; i < 4; ++i)
                rmin[pt][i] = fminf(rmin[pt][i], __shfl_xor(rmin[pt][i], mm));
        #pragma unroll
        for (int i = 0; i < 4; ++i) thr[pt][i] = rmin[pt][i] + TAU;
    }

    // ---- D: sweep 2 — bit-identical recompute, candidate append vs thr
    {
        bf16x8 c0 = FRAG(0, 0, 0), c1 = FRAG(0, 0, 1);
        bf16x8 c2 = FRAG(1, 0, 0), c3 = FRAG(1, 0, 1);
        float wa = wwlds[(l & 15)];
        f32x4 acc;
        #pragma unroll 1
        for (int ct = 0; ct < 32; ++ct) {
            const int nt = (ct + 1) & 31;
            bf16x8 p0 = FRAG(0, nt, 0), p1 = FRAG(0, nt, 1);
            bf16x8 p2 = FRAG(1, nt, 0), p3 = FRAG(1, nt, 1);
            float wb = wwlds[nt * 16 + (l & 15)];
            #pragma unroll
            for (int pt = 0; pt < 4; ++pt) {
                TILE6(pt, c0, c1, c2, c3, wa)
                const int prow = (wv * 4 + pt) * 16 + rloc;
                #pragma unroll
                for (int i = 0; i < 4; ++i) {
                    if (acc[i] <= thr[pt][i]) {
                        int s = atomicAdd(&ccount[prow + i], 1);
                        if (s < 4) clist[(prow + i) * 4 + s] = ct * 16 + (l & 15);
                    }
                }
            }
            {   // zero-fill second half -> [16384, 32768), guard the edge
                const int mb = 16384 + ct * (TB * 2) + tid;
                zs4[mb]       = zero4;
                if (mb + TB < NF4) zs4[mb + TB] = zero4;
                const int mb2 = 16384 + (TB * 64) + ct * (TB * 2) + tid;
                if (mb2 < NF4)      zs4[mb2]      = zero4;
                if (mb2 + TB < NF4) zs4[mb2 + TB] = zero4;
            }
            c0 = p0; c1 = p1; c2 = p2; c3 = p3; wa = wb;
        }
    }

    __syncthreads();   // clists complete; zero-fill drained (vmcnt(0) at barrier)

    // ---- E: rescue — wave wv owns positions wv*64 .. wv*64+63 (lane = one)
    {
        const int p = wv * 64 + l;             // position within block
        const int cnt = ccount[p];
        int bk;
        if (cnt == 1) {
            bk = clist[p * 4 + 0];
        } else {
            float x2c[DIM];
            float r[8];
            #pragma unroll
            for (int d = 0; d < DIM; ++d) {
                float v = xtile[d][p];
                x2c[d] = v + v;                  // exact doubling
                float pp = __fmul_rn(v, v);
                r[d & 7] = (d < 8) ? pp : __fadd_rn(r[d & 7], pp);
            }
            const float A = tree8(r[0], r[1], r[2], r[3], r[4], r[5], r[6], r[7]);
            if (cnt <= 4) {
                float bd = INFINITY; int bk2 = KCODES;
                for (int c = 0; c < cnt; ++c) {
                    const int k = clist[p * 4 + c];
                    const float* wk = w + (size_t)k * DIM;
                    float s[8];
                    #pragma unroll
                    for (int i = 0; i < 8; ++i) {
                        #pragma unroll
                        for (int j = 0; j < 8; ++j) {
                            const int d = i * 8 + j;
                            float wvv = wk[d];
                            if (i == 0) s[j] = __fmul_rn(x2c[d], wvv);
                            else        s[j] = __fmaf_rn(x2c[d], wvv, s[j]);
                        }
                    }
                    float dot  = tree8(s[0], s[1], s[2], s[3], s[4], s[5], s[6], s[7]);
                    float dist = __fadd_rn(__fadd_rn(A, wwlds[k]), -dot);
                    if (dist < bd || (dist == bd && k < bk2)) { bd = dist; bk2 = k; }
                }
                bk = bk2;
            } else {                             // guaranteed path (≈never)
                float bd = INFINITY; int bk2 = 0;
                #pragma unroll 1
                for (int k = 0; k < KCODES; ++k) {
                    const float* wk = w + (size_t)k * DIM;
                    float s[8];
                    #pragma unroll
                    for (int i = 0; i < 8; ++i) {
                        #pragma unroll
                        for (int j = 0; j < 8; ++j) {
                            const int d = i * 8 + j;
                            float wvv = wk[d];
                            if (i == 0) s[j] = __fmul_rn(x2c[d], wvv);
                            else        s[j] = __fmaf_rn(x2c[d], wvv, s[j]);
                        }
                    }
                    float dot  = tree8(s[0], s[1], s[2], s[3], s[4], s[5], s[6], s[7]);
                    float dist = __fadd_rn(__fadd_rn(A, wwlds[k]), -dot);
                    if (dist < bd) { bd = dist; bk2 = k; }   // ascending strict <
                }
                bk = bk2;
            }
        }
        bestkL[p] = bk;
        out[ENC_OFF + (size_t)(n0 + p) * KCODES + bk] = 1.0f;   // one-hot
        atomicAdd(&hcount[bk], 1);
    }

    __syncthreads();   // bestkL visible; hcount atomics ordered before drain

    // ---- F: parallel epilogue — thread tid owns position tid (64 channels)
    {
        const int sp = tid;
        const int bk = bestkL[sp];
        const float4* wr = reinterpret_cast<const float4*>(w + (size_t)bk * DIM);
        float* qo = out + ((size_t)b * DIM) * HW + (hw0 + sp);
        float sse = 0.0f;
        #pragma unroll
        for (int c = 0; c < 16; ++c) {
            float4 qv = wr[c];
            const int ch = c * 4;
            qo[(size_t)(ch + 0) * HW] = qv.x;
            qo[(size_t)(ch + 1) * HW] = qv.y;
            qo[(size_t)(ch + 2) * HW] = qv.z;
            qo[(size_t)(ch + 3) * HW] = qv.w;
            float e0 = qv.x - xtile[ch + 0][sp]; sse = __fmaf_rn(e0, e0, sse);
            float e1 = qv.y - xtile[ch + 1][sp]; sse = __fmaf_rn(e1, e1, sse);
            float e2 = qv.z - xtile[ch + 2][sp]; sse = __fmaf_rn(e2, e2, sse);
            float e3 = qv.w - xtile[ch + 3][sp]; sse = __fmaf_rn(e3, e3, sse);
        }
        #pragma unroll
        for (int off = 32; off > 0; off >>= 1) sse += __shfl_down(sse, off);
        if (l == 0) atomicAdd(lossAcc, sse);
    }

    __syncthreads();   // all hcount traffic done

    // histogram drain
    {
        int c0 = hcount[tid];       if (c0) atomicAdd(&counts[tid], c0);
        int c1 = hcount[tid + TB];  if (c1) atomicAdd(&counts[tid + TB], c1);
    }
}

// Finalize: loss scalar + perplexity from histogram.
extern "C" __global__ __launch_bounds__(512)
void vq_finalize(const int* __restrict__ counts, const float* __restrict__ lossAcc,
                 float* __restrict__ out)
{
    __shared__ double sred[KCODES];
    const int t = threadIdx.x;                 // 512 threads
    double p = (double)counts[t] * (1.0 / (double)NPOS);
    sred[t] = -p * log(p + 1e-10);
    __syncthreads();
    for (int s = KCODES / 2; s > 0; s >>= 1) {
        if (t < s) sred[t] += sred[t + s];
        __syncthreads();
    }
    if (t == 0) {
        out[PERP_OFF] = (float)exp(sred[0]);
        out[LOSS_OFF] = 1.25f * (lossAcc[0] / 8388608.0f);
    }
}

extern "C" void kernel_launch(void* const* d_in, const int* in_sizes, int n_in,
                              void* d_out, int out_size, void* d_ws, size_t ws_size,
                              hipStream_t stream)
{
    const float* x = (const float*)d_in[0];    // [32,64,64,64] fp32
    const float* w = (const float*)d_in[1];    // [512,64] fp32
    float* out = (float*)d_out;

    float* ww              = (float*)d_ws;                       // 512 floats
    int*   counts          = (int*)((char*)d_ws + 2048);         // 512 ints
    float* lossAcc         = (float*)((char*)d_ws + 4096);       // 1 float
    unsigned short* wfrag  = (unsigned short*)((char*)d_ws + 8192);  // 128KB

    vq_prep<<<33, 512, 0, stream>>>(w, ww, counts, lossAcc, wfrag);
    vq_main<<<NPOS / POSB, TB, 0, stream>>>(x, w, ww, out, counts,
                                            lossAcc, wfrag);
    vq_finalize<<<1, 512, 0, stream>>>(counts, lossAcc, out);
}